// Round 2
// baseline (1435.718 us; speedup 1.0000x reference)
//
#include <hip/hip_runtime.h>
#include <stdint.h>

typedef __bf16 bf16;
typedef __bf16 bf16x4 __attribute__((ext_vector_type(4)));
typedef __bf16 bf16x8 __attribute__((ext_vector_type(8)));
typedef float  f32x4  __attribute__((ext_vector_type(4)));

__device__ __forceinline__ int clampi(int v, int n) { return (v < 0 || v >= n) ? 0 : v; }

// W [K][256] f32 -> Wt [256][K] bf16
__global__ void wtcvt_kernel(const float* __restrict__ W, bf16* __restrict__ Wt, int K) {
  int idx = blockIdx.x * 256 + threadIdx.x;
  if (idx >= K * 256) return;
  int k = idx >> 8, n = idx & 255;
  Wt[(size_t)n * K + k] = (bf16)W[idx];
}

// ---------------- CSR build ----------------
__global__ void hist_kernel(const int* __restrict__ dst, int E, int* __restrict__ cnt, int N) {
  int e = blockIdx.x * 256 + threadIdx.x;
  if (e < E) atomicAdd(&cnt[clampi(dst[e], N)], 1);
}

__global__ void scan_block_kernel(const int* __restrict__ cnt, int N,
                                  int* __restrict__ incl, int* __restrict__ bsums) {
  __shared__ int sd[256];
  int t = threadIdx.x, bid = blockIdx.x;
  int base = bid * 1024 + t * 4;
  int v0 = (base + 0 < N) ? cnt[base + 0] : 0;
  int v1 = (base + 1 < N) ? cnt[base + 1] : 0;
  int v2 = (base + 2 < N) ? cnt[base + 2] : 0;
  int v3 = (base + 3 < N) ? cnt[base + 3] : 0;
  int s1 = v0 + v1, s2 = s1 + v2, s3 = s2 + v3;
  sd[t] = s3;
  __syncthreads();
  for (int off = 1; off < 256; off <<= 1) {
    int x = 0;
    if (t >= off) x = sd[t - off];
    __syncthreads();
    sd[t] += x;
    __syncthreads();
  }
  int excl = sd[t] - s3;
  if (base + 0 < N) incl[base + 0] = excl + v0;
  if (base + 1 < N) incl[base + 1] = excl + s1;
  if (base + 2 < N) incl[base + 2] = excl + s2;
  if (base + 3 < N) incl[base + 3] = excl + s3;
  if (t == 255) bsums[bid] = sd[255];
}

__global__ void scan_sums_kernel(const int* __restrict__ bsums, int nb, int* __restrict__ bexcl) {
  __shared__ int sd[256];
  int t = threadIdx.x;
  int v = (t < nb) ? bsums[t] : 0;
  sd[t] = v;
  __syncthreads();
  for (int off = 1; off < 256; off <<= 1) {
    int x = 0;
    if (t >= off) x = sd[t - off];
    __syncthreads();
    sd[t] += x;
    __syncthreads();
  }
  if (t < nb) bexcl[t] = sd[t] - v;
}

__global__ void scan_add_kernel(const int* __restrict__ incl, const int* __restrict__ bexcl,
                                int N, int* __restrict__ offs) {
  int i = blockIdx.x * 256 + threadIdx.x;
  if (i < N) offs[i + 1] = incl[i] + bexcl[i >> 10];
  if (i == 0) offs[0] = 0;
}

__global__ void scatter_kernel(const int* __restrict__ dst, int E, const int* __restrict__ offs,
                               int* __restrict__ cursor, int* __restrict__ elist, int N) {
  int e = blockIdx.x * 256 + threadIdx.x;
  if (e < E) {
    int d = clampi(dst[e], N);
    int p = atomicAdd(&cursor[d], 1);
    elist[offs[d] + p] = e;
  }
}

// ---------------- segment sum (one wave per node, 4 cols/lane) ----------------
template <int WHERE, int XF32>
__global__ void segsum_kernel(const bf16* __restrict__ H, const int* __restrict__ elist,
                              const int* __restrict__ offs, const float* __restrict__ xf,
                              const bf16* __restrict__ xb, bf16* __restrict__ out, int N) {
  int lane = threadIdx.x & 63;
  int node = blockIdx.x * 4 + (threadIdx.x >> 6);
  if (node >= N) return;
  int beg = offs[node], end = offs[node + 1];
  float a0 = 0.f, a1 = 0.f, a2 = 0.f, a3 = 0.f;
  for (int p = beg; p < end; ++p) {
    int e = elist[p];
    bf16x4 v = ((const bf16x4*)(H + (size_t)e * 256))[lane];
    a0 += (float)v[0]; a1 += (float)v[1]; a2 += (float)v[2]; a3 += (float)v[3];
  }
  if (WHERE) {
    float s = a0 + a1 + a2 + a3;
    for (int off = 1; off < 64; off <<= 1) s += __shfl_xor(s, off);
    if (s == 0.f) {  // no (nonzero) incoming messages -> pass through x
      bf16x4 o;
      if (XF32) {
        float4 xv = ((const float4*)(xf))[(size_t)node * 64 + lane];
        o[0] = (bf16)xv.x; o[1] = (bf16)xv.y; o[2] = (bf16)xv.z; o[3] = (bf16)xv.w;
      } else {
        o = ((const bf16x4*)(xb + (size_t)node * 256))[lane];
      }
      ((bf16x4*)(out + (size_t)node * 256))[lane] = o;
      return;
    }
  }
  bf16x4 o = {(bf16)a0, (bf16)a1, (bf16)a2, (bf16)a3};
  ((bf16x4*)(out + (size_t)node * 256))[lane] = o;
}

// ---------------- mean pool over contiguous groups ----------------
template <int OUTF32>
__global__ void pool_kernel(const bf16* __restrict__ h, bf16* __restrict__ outb,
                            float* __restrict__ outf, int Nout, int cnt) {
  int lane = threadIdx.x & 63;
  int node = blockIdx.x * 4 + (threadIdx.x >> 6);
  if (node >= Nout) return;
  float a0 = 0.f, a1 = 0.f, a2 = 0.f, a3 = 0.f;
  size_t base = (size_t)node * cnt;
  for (int p = 0; p < cnt; ++p) {
    bf16x4 v = ((const bf16x4*)(h + (base + p) * 256))[lane];
    a0 += (float)v[0]; a1 += (float)v[1]; a2 += (float)v[2]; a3 += (float)v[3];
  }
  float c = (float)cnt;
  a0 /= c; a1 /= c; a2 /= c; a3 /= c;
  if (OUTF32) {
    float4 o = {a0, a1, a2, a3};
    ((float4*)(outf + (size_t)node * 256))[lane] = o;
  } else {
    bf16x4 o = {(bf16)a0, (bf16)a1, (bf16)a2, (bf16)a3};
    ((bf16x4*)(outb + (size_t)node * 256))[lane] = o;
  }
}

// ---------------- fused gather-GEMM (register staging, XOR-swizzled LDS) ----
// out[row, n] = relu( A_row @ Wt^T + bias [+ H0] ), bf16 [Mrows][256]
// MODE 0: A_row(e) = concat(x[src[e]] (256), ea[e] (64 f32)), K=320
// MODE 1: A_row(e) = agg[src[e]] - Hin[rev[e]], K=256, adds H0[e]; out may alias H0
// MODE 2: A_row(n) = concat(x[n], agg[n]), K=512
// XF32: x rows read as f32 (level 1) vs bf16 (levels 2/3)
template <int MODE, int XF32>
__global__ __launch_bounds__(256, 2) void gemm_kernel(
    const float* __restrict__ A1f, const bf16* __restrict__ A1b,
    const float* __restrict__ A2f, const bf16* __restrict__ A2b,
    const bf16* __restrict__ Wt, const float* __restrict__ bias, const bf16* H0,
    const int* __restrict__ srcIdx, const int* __restrict__ revIdx,
    bf16* out, int Mrows, int K, int Nsrc) {
  __shared__ __align__(16) bf16 As[128 * 64];
  __shared__ __align__(16) bf16 Bs[128 * 64];
  int tid = threadIdx.x;
  int lane = tid & 63;
  int wave = tid >> 6;
  int wm = wave >> 1, wn = wave & 1;
  int m0 = blockIdx.x * 128;
  int n0 = blockIdx.y * 128;

  f32x4 acc[4][4];
#pragma unroll
  for (int i = 0; i < 4; ++i)
#pragma unroll
    for (int j = 0; j < 4; ++j) acc[i][j] = (f32x4){0.f, 0.f, 0.f, 0.f};

  int nk = K / 64;
  for (int kc = 0; kc < nk; ++kc) {
    int k0 = kc * 64;
    __syncthreads();
    // ---- stage B: Bs holds Wt[n0+row][k0 + chunk], chunk XOR-swizzled ----
#pragma unroll
    for (int r = 0; r < 4; ++r) {
      int unit = r * 256 + tid;
      int row = unit >> 3, u = unit & 7, us = u ^ (row & 7);
      bf16x8 v = *(const bf16x8*)(Wt + (size_t)(n0 + row) * K + k0 + u * 8);
      *(bf16x8*)(&Bs[(size_t)(row * 8 + us) * 8]) = v;
    }
    // ---- stage A ----
#pragma unroll
    for (int r = 0; r < 4; ++r) {
      int unit = r * 256 + tid;
      int row = unit >> 3, u = unit & 7, us = u ^ (row & 7);
      int rr = m0 + row;
      if (rr >= Mrows) rr = Mrows - 1;
      bf16x8 v;
      if (MODE == 0) {
        if (k0 < 256) {
          int sn = clampi(srcIdx[rr], Nsrc);
          if (XF32) {
            const float* g = A1f + (size_t)sn * 256 + k0 + u * 8;
            float4 a = *(const float4*)g, b = *(const float4*)(g + 4);
            v[0] = (bf16)a.x; v[1] = (bf16)a.y; v[2] = (bf16)a.z; v[3] = (bf16)a.w;
            v[4] = (bf16)b.x; v[5] = (bf16)b.y; v[6] = (bf16)b.z; v[7] = (bf16)b.w;
          } else {
            v = *(const bf16x8*)(A1b + (size_t)sn * 256 + k0 + u * 8);
          }
        } else {
          const float* g = A2f + (size_t)rr * 64 + (k0 - 256) + u * 8;
          float4 a = *(const float4*)g, b = *(const float4*)(g + 4);
          v[0] = (bf16)a.x; v[1] = (bf16)a.y; v[2] = (bf16)a.z; v[3] = (bf16)a.w;
          v[4] = (bf16)b.x; v[5] = (bf16)b.y; v[6] = (bf16)b.z; v[7] = (bf16)b.w;
        }
      } else if (MODE == 1) {
        int sn = clampi(srcIdx[rr], Nsrc);
        int rv = clampi(revIdx[rr], Mrows);
        bf16x8 va = *(const bf16x8*)(A1b + (size_t)sn * 256 + k0 + u * 8);
        bf16x8 vh = *(const bf16x8*)(A2b + (size_t)rv * 256 + k0 + u * 8);
#pragma unroll
        for (int j = 0; j < 8; ++j) v[j] = (bf16)((float)va[j] - (float)vh[j]);
      } else {  // MODE 2
        if (k0 < 256) {
          if (XF32) {
            const float* g = A1f + (size_t)rr * 256 + k0 + u * 8;
            float4 a = *(const float4*)g, b = *(const float4*)(g + 4);
            v[0] = (bf16)a.x; v[1] = (bf16)a.y; v[2] = (bf16)a.z; v[3] = (bf16)a.w;
            v[4] = (bf16)b.x; v[5] = (bf16)b.y; v[6] = (bf16)b.z; v[7] = (bf16)b.w;
          } else {
            v = *(const bf16x8*)(A1b + (size_t)rr * 256 + k0 + u * 8);
          }
        } else {
          v = *(const bf16x8*)(A2b + (size_t)rr * 256 + (k0 - 256) + u * 8);
        }
      }
      *(bf16x8*)(&As[(size_t)(row * 8 + us) * 8]) = v;
    }
    __syncthreads();
    // ---- compute: 2 k-subtiles of 32, 32 MFMA per wave per K-tile ----
#pragma unroll
    for (int s = 0; s < 2; ++s) {
      int kq = s * 4 + (lane >> 4);
      bf16x8 af[4], bfr[4];
#pragma unroll
      for (int i = 0; i < 4; ++i) {
        int arow = wm * 64 + i * 16 + (lane & 15);
        af[i] = *(const bf16x8*)(&As[(size_t)arow * 64 + (size_t)(kq ^ (arow & 7)) * 8]);
      }
#pragma unroll
      for (int j = 0; j < 4; ++j) {
        int brow = wn * 64 + j * 16 + (lane & 15);
        bfr[j] = *(const bf16x8*)(&Bs[(size_t)brow * 64 + (size_t)(kq ^ (brow & 7)) * 8]);
      }
#pragma unroll
      for (int i = 0; i < 4; ++i)
#pragma unroll
        for (int j = 0; j < 4; ++j)
          acc[i][j] = __builtin_amdgcn_mfma_f32_16x16x32_bf16(af[i], bfr[j], acc[i][j], 0, 0, 0);
    }
  }
  // ---- epilogue: D row=(lane>>4)*4+r, col=lane&15 ----
#pragma unroll
  for (int i = 0; i < 4; ++i) {
    int rbase = m0 + wm * 64 + i * 16 + ((lane >> 4) << 2);
#pragma unroll
    for (int j = 0; j < 4; ++j) {
      int col = n0 + wn * 64 + j * 16 + (lane & 15);
      float bcol = bias[col];
#pragma unroll
      for (int r = 0; r < 4; ++r) {
        int row = rbase + r;
        if (row < Mrows) {
          float v = acc[i][j][r] + bcol;
          if (MODE == 1) v += (float)H0[(size_t)row * 256 + col];  // read-before-write when out==H0
          v = fmaxf(v, 0.f);
          out[(size_t)row * 256 + col] = (bf16)v;
        }
      }
    }
  }
}

// ---------------- per-level driver ----------------
template <int XF32>
static void run_level(const float* xf, const bf16* xb, const float* ea,
                      const int* src, const int* dst, const int* rev, int E, int N, int depth,
                      const bf16* WiT, const float* bi_, const bf16* WhT, const float* bh_,
                      const bf16* WoT, const float* bo_,
                      bf16* C, bf16* Dd, bf16* Ee, bf16* agg, bf16* h,
                      int* cnt, int* incl, int* offs, int* cursr, int* bsums, int* bexcl,
                      int* elist, hipStream_t stream) {
  // CSR build
  hipMemsetAsync(cnt, 0, (size_t)N * 4, stream);
  hist_kernel<<<(E + 255) / 256, 256, 0, stream>>>(dst, E, cnt, N);
  int nb = (N + 1023) / 1024;
  scan_block_kernel<<<nb, 256, 0, stream>>>(cnt, N, incl, bsums);
  scan_sums_kernel<<<1, 256, 0, stream>>>(bsums, nb, bexcl);
  scan_add_kernel<<<(N + 255) / 256, 256, 0, stream>>>(incl, bexcl, N, offs);
  hipMemsetAsync(cursr, 0, (size_t)N * 4, stream);
  scatter_kernel<<<(E + 255) / 256, 256, 0, stream>>>(dst, E, offs, cursr, elist, N);

  dim3 ge((E + 127) / 128, 2);
  // H0 = relu([x[src], ea] @ Wi + bi) -> C
  gemm_kernel<0, XF32><<<ge, 256, 0, stream>>>(xf, xb, ea, nullptr, WiT, bi_, nullptr, src,
                                               nullptr, C, E, 320, N);
  bf16* Hcur = C;
  for (int it = 0; it < depth - 1; ++it) {
    segsum_kernel<0, 0><<<(N + 3) / 4, 256, 0, stream>>>(Hcur, elist, offs, nullptr, nullptr,
                                                         agg, N);
    bf16* Hn = (it == depth - 2) ? C : ((it & 1) ? Ee : Dd);  // last iter writes H0 in place
    gemm_kernel<1, 0><<<ge, 256, 0, stream>>>(nullptr, agg, nullptr, Hcur, WhT, bh_, C, src,
                                              rev, Hn, E, 256, N);
    Hcur = Hn;
  }
  segsum_kernel<1, XF32><<<(N + 3) / 4, 256, 0, stream>>>(Hcur, elist, offs, xf, xb, agg, N);
  dim3 gn((N + 127) / 128, 2);
  // h = relu([x, M] @ Wo + bo)
  gemm_kernel<2, XF32><<<gn, 256, 0, stream>>>(xf, xb, nullptr, agg, WoT, bo_, nullptr, nullptr,
                                               nullptr, h, N, 512, N);
}

// ---------------- host ----------------
extern "C" void kernel_launch(void* const* d_in, const int* in_sizes, int n_in,
                              void* d_out, int out_size, void* d_ws, size_t ws_size,
                              hipStream_t stream) {
  constexpr int N1 = 102400, E1 = 300000;
  constexpr int N2 = 10240, E2 = 40960;
  constexpr int N3 = 1024, E3 = 4096;
  constexpr int G = 64;
  constexpr int KI = 320, KH = 256, KO = 512;

  const float* x   = (const float*)d_in[0];
  const float* ea1 = (const float*)d_in[1];
  const float* ea2 = (const float*)d_in[2];
  const float* ea3 = (const float*)d_in[3];
  const int* ei1 = (const int*)d_in[4];
  const int* rv1 = (const int*)d_in[5];
  const int* ei2 = (const int*)d_in[6];
  const int* rv2 = (const int*)d_in[7];
  const int* ei3 = (const int*)d_in[8];
  const int* rv3 = (const int*)d_in[9];
  const float *Wi[3], *bi[3], *Wh[3], *bh[3], *Wo[3], *bo[3];
  for (int l = 0; l < 3; ++l) {
    Wi[l] = (const float*)d_in[13 + 6 * l + 0];
    bi[l] = (const float*)d_in[13 + 6 * l + 1];
    Wh[l] = (const float*)d_in[13 + 6 * l + 2];
    bh[l] = (const float*)d_in[13 + 6 * l + 3];
    Wo[l] = (const float*)d_in[13 + 6 * l + 4];
    bo[l] = (const float*)d_in[13 + 6 * l + 5];
  }
  float* outp = (float*)d_out;
  char* ws = (char*)d_ws;

  size_t off = 0;
  auto alloc = [&](size_t b) { size_t o = off; off += (b + 255) & ~(size_t)255; return o; };
  size_t o_wit[3], o_wht[3], o_wot[3];
  for (int l = 0; l < 3; ++l) {
    o_wit[l] = alloc((size_t)256 * KI * 2);
    o_wht[l] = alloc((size_t)256 * KH * 2);
    o_wot[l] = alloc((size_t)256 * KO * 2);
  }
  size_t o_C   = alloc((size_t)E1 * 256 * 2);  // H0 / in-place H_final / h1
  size_t o_D   = alloc((size_t)E1 * 256 * 2);  // ping buffer
  size_t o_E3b = alloc((size_t)E3 * 256 * 2);  // level-3 (depth 4) pong buffer
  size_t o_agg = alloc((size_t)N1 * 256 * 2);
  size_t o_x2  = alloc((size_t)N2 * 256 * 2);
  size_t o_h2  = alloc((size_t)N2 * 256 * 2);
  size_t o_x3  = alloc((size_t)N3 * 256 * 2);
  size_t o_h3  = alloc((size_t)N3 * 256 * 2);
  size_t o_cnt = alloc((size_t)N1 * 4);
  size_t o_inc = alloc((size_t)N1 * 4);
  size_t o_off = alloc((size_t)(N1 + 1) * 4);
  size_t o_cur = alloc((size_t)N1 * 4);
  size_t o_bs  = alloc(1024 * 4);
  size_t o_bx  = alloc(1024 * 4);
  size_t o_el  = alloc((size_t)E1 * 4);

  if (ws_size < off) {  // workspace too small: fail validation cleanly, don't fault
    hipMemsetAsync(d_out, 0, (size_t)out_size * 4, stream);
    return;
  }

  int* cnt   = (int*)(ws + o_cnt);
  int* incl  = (int*)(ws + o_inc);
  int* offs  = (int*)(ws + o_off);
  int* cursr = (int*)(ws + o_cur);
  int* bsums = (int*)(ws + o_bs);
  int* bexcl = (int*)(ws + o_bx);
  int* elist = (int*)(ws + o_el);
  bf16* C    = (bf16*)(ws + o_C);
  bf16* Dd   = (bf16*)(ws + o_D);
  bf16* E3b  = (bf16*)(ws + o_E3b);
  bf16* agg  = (bf16*)(ws + o_agg);
  bf16* x2b  = (bf16*)(ws + o_x2);
  bf16* h2b  = (bf16*)(ws + o_h2);
  bf16* x3b  = (bf16*)(ws + o_x3);
  bf16* h3b  = (bf16*)(ws + o_h3);

  for (int l = 0; l < 3; ++l) {
    wtcvt_kernel<<<(KI * 256 + 255) / 256, 256, 0, stream>>>(Wi[l], (bf16*)(ws + o_wit[l]), KI);
    wtcvt_kernel<<<(KH * 256 + 255) / 256, 256, 0, stream>>>(Wh[l], (bf16*)(ws + o_wht[l]), KH);
    wtcvt_kernel<<<(KO * 256 + 255) / 256, 256, 0, stream>>>(Wo[l], (bf16*)(ws + o_wot[l]), KO);
  }

  // level 1 (x as f32; h1 written into C after final segsum consumed it)
  run_level<1>(x, nullptr, ea1, ei1, ei1 + E1, rv1, E1, N1, 3,
               (bf16*)(ws + o_wit[0]), bi[0], (bf16*)(ws + o_wht[0]), bh[0],
               (bf16*)(ws + o_wot[0]), bo[0], C, Dd, Dd, agg, C,
               cnt, incl, offs, cursr, bsums, bexcl, elist, stream);
  pool_kernel<0><<<(N2 + 3) / 4, 256, 0, stream>>>(C, x2b, nullptr, N2, N1 / N2);

  // level 2 (C/Dd regions are dead now; reuse their space)
  run_level<0>(nullptr, x2b, ea2, ei2, ei2 + E2, rv2, E2, N2, 3,
               (bf16*)(ws + o_wit[1]), bi[1], (bf16*)(ws + o_wht[1]), bh[1],
               (bf16*)(ws + o_wot[1]), bo[1], C, Dd, Dd, agg, h2b,
               cnt, incl, offs, cursr, bsums, bexcl, elist, stream);
  pool_kernel<0><<<(N3 + 3) / 4, 256, 0, stream>>>(h2b, x3b, nullptr, N3, N2 / N3);

  // level 3 (depth 4 -> needs distinct pong buffer E3b)
  run_level<0>(nullptr, x3b, ea3, ei3, ei3 + E3, rv3, E3, N3, 4,
               (bf16*)(ws + o_wit[2]), bi[2], (bf16*)(ws + o_wht[2]), bh[2],
               (bf16*)(ws + o_wot[2]), bo[2], C, Dd, E3b, agg, h3b,
               cnt, incl, offs, cursr, bsums, bexcl, elist, stream);
  pool_kernel<1><<<(G + 3) / 4, 256, 0, stream>>>(h3b, nullptr, outp, G, N3 / G);
}

// Round 3
// 1289.895 us; speedup vs baseline: 1.1130x; 1.1130x over previous
//
#include <hip/hip_runtime.h>
#include <stdint.h>

typedef __bf16 bf16;
typedef __bf16 bf16x4 __attribute__((ext_vector_type(4)));
typedef __bf16 bf16x8 __attribute__((ext_vector_type(8)));
typedef float  f32x4  __attribute__((ext_vector_type(4)));

__device__ __forceinline__ int clampi(int v, int n) { return (v < 0 || v >= n) ? 0 : v; }

__device__ __forceinline__ void gload16(const void* g, void* l) {
  __builtin_amdgcn_global_load_lds((const __attribute__((address_space(1))) void*)g,
                                   (__attribute__((address_space(3))) void*)l, 16, 0, 0);
}

// W [K][256] f32 -> Wt [256][K] bf16
__global__ void wtcvt_kernel(const float* __restrict__ W, bf16* __restrict__ Wt, int K) {
  int idx = blockIdx.x * 256 + threadIdx.x;
  if (idx >= K * 256) return;
  int k = idx >> 8, n = idx & 255;
  Wt[(size_t)n * K + k] = (bf16)W[idx];
}

// ---------------- CSR build ----------------
__global__ void hist_kernel(const int* __restrict__ dst, int E, int* __restrict__ cnt, int N) {
  int e = blockIdx.x * 256 + threadIdx.x;
  if (e < E) atomicAdd(&cnt[clampi(dst[e], N)], 1);
}

__global__ void scan_block_kernel(const int* __restrict__ cnt, int N,
                                  int* __restrict__ incl, int* __restrict__ bsums) {
  __shared__ int sd[256];
  int t = threadIdx.x, bid = blockIdx.x;
  int base = bid * 1024 + t * 4;
  int v0 = (base + 0 < N) ? cnt[base + 0] : 0;
  int v1 = (base + 1 < N) ? cnt[base + 1] : 0;
  int v2 = (base + 2 < N) ? cnt[base + 2] : 0;
  int v3 = (base + 3 < N) ? cnt[base + 3] : 0;
  int s1 = v0 + v1, s2 = s1 + v2, s3 = s2 + v3;
  sd[t] = s3;
  __syncthreads();
  for (int off = 1; off < 256; off <<= 1) {
    int x = 0;
    if (t >= off) x = sd[t - off];
    __syncthreads();
    sd[t] += x;
    __syncthreads();
  }
  int excl = sd[t] - s3;
  if (base + 0 < N) incl[base + 0] = excl + v0;
  if (base + 1 < N) incl[base + 1] = excl + s1;
  if (base + 2 < N) incl[base + 2] = excl + s2;
  if (base + 3 < N) incl[base + 3] = excl + s3;
  if (t == 255) bsums[bid] = sd[255];
}

__global__ void scan_sums_kernel(const int* __restrict__ bsums, int nb, int* __restrict__ bexcl) {
  __shared__ int sd[256];
  int t = threadIdx.x;
  int v = (t < nb) ? bsums[t] : 0;
  sd[t] = v;
  __syncthreads();
  for (int off = 1; off < 256; off <<= 1) {
    int x = 0;
    if (t >= off) x = sd[t - off];
    __syncthreads();
    sd[t] += x;
    __syncthreads();
  }
  if (t < nb) bexcl[t] = sd[t] - v;
}

__global__ void scan_add_kernel(const int* __restrict__ incl, const int* __restrict__ bexcl,
                                int N, int* __restrict__ offs) {
  int i = blockIdx.x * 256 + threadIdx.x;
  if (i < N) offs[i + 1] = incl[i] + bexcl[i >> 10];
  if (i == 0) offs[0] = 0;
}

__global__ void scatter_kernel(const int* __restrict__ dst, int E, const int* __restrict__ offs,
                               int* __restrict__ cursor, int* __restrict__ elist, int N) {
  int e = blockIdx.x * 256 + threadIdx.x;
  if (e < E) {
    int d = clampi(dst[e], N);
    int p = atomicAdd(&cursor[d], 1);
    elist[offs[d] + p] = e;
  }
}

// ---------------- segment sum (one wave per node, 4 cols/lane) ----------------
template <int WHERE, int XF32>
__global__ void segsum_kernel(const bf16* __restrict__ H, const int* __restrict__ elist,
                              const int* __restrict__ offs, const float* __restrict__ xf,
                              const bf16* __restrict__ xb, bf16* __restrict__ out, int N) {
  int lane = threadIdx.x & 63;
  int node = blockIdx.x * 4 + (threadIdx.x >> 6);
  if (node >= N) return;
  int beg = offs[node], end = offs[node + 1];
  float a0 = 0.f, a1 = 0.f, a2 = 0.f, a3 = 0.f;
  for (int p = beg; p < end; ++p) {
    int e = elist[p];
    bf16x4 v = ((const bf16x4*)(H + (size_t)e * 256))[lane];
    a0 += (float)v[0]; a1 += (float)v[1]; a2 += (float)v[2]; a3 += (float)v[3];
  }
  if (WHERE) {
    float s = a0 + a1 + a2 + a3;
    for (int off = 1; off < 64; off <<= 1) s += __shfl_xor(s, off);
    if (s == 0.f) {  // no (nonzero) incoming messages -> pass through x
      bf16x4 o;
      if (XF32) {
        float4 xv = ((const float4*)(xf))[(size_t)node * 64 + lane];
        o[0] = (bf16)xv.x; o[1] = (bf16)xv.y; o[2] = (bf16)xv.z; o[3] = (bf16)xv.w;
      } else {
        o = ((const bf16x4*)(xb + (size_t)node * 256))[lane];
      }
      ((bf16x4*)(out + (size_t)node * 256))[lane] = o;
      return;
    }
  }
  bf16x4 o = {(bf16)a0, (bf16)a1, (bf16)a2, (bf16)a3};
  ((bf16x4*)(out + (size_t)node * 256))[lane] = o;
}

// ---------------- mean pool over contiguous groups ----------------
template <int OUTF32>
__global__ void pool_kernel(const bf16* __restrict__ h, bf16* __restrict__ outb,
                            float* __restrict__ outf, int Nout, int cnt) {
  int lane = threadIdx.x & 63;
  int node = blockIdx.x * 4 + (threadIdx.x >> 6);
  if (node >= Nout) return;
  float a0 = 0.f, a1 = 0.f, a2 = 0.f, a3 = 0.f;
  size_t base = (size_t)node * cnt;
  for (int p = 0; p < cnt; ++p) {
    bf16x4 v = ((const bf16x4*)(h + (base + p) * 256))[lane];
    a0 += (float)v[0]; a1 += (float)v[1]; a2 += (float)v[2]; a3 += (float)v[3];
  }
  float c = (float)cnt;
  a0 /= c; a1 /= c; a2 /= c; a3 /= c;
  if (OUTF32) {
    float4 o = {a0, a1, a2, a3};
    ((float4*)(outf + (size_t)node * 256))[lane] = o;
  } else {
    bf16x4 o = {(bf16)a0, (bf16)a1, (bf16)a2, (bf16)a3};
    ((bf16x4*)(outb + (size_t)node * 256))[lane] = o;
  }
}

// ---------------- fused gather-GEMM, pipelined ----------------
// 512 threads, BM=128, BN=256 (full width), BK=64. Per-wave 64x64, acc[4][4].
// A: register-prefetched one K-tile ahead (gathers); B: global_load_lds from Wt.
// out[row, n] = relu( A_row @ Wt^T + bias [+ H0] ), bf16 [Mrows][256]
// MODE 0: A_row(e) = concat(x[src[e]] (256), ea[e] (64 f32)), K=320
// MODE 1: A_row(e) = agg[src[e]] - Hin[rev[e]], K=256, adds H0[e]; out may alias H0
// MODE 2: A_row(n) = concat(x[n], agg[n]), K=512
template <int MODE, int XF32>
__global__ __launch_bounds__(512, 4) void gemm_kernel(
    const float* __restrict__ A1f, const bf16* __restrict__ A1b,
    const float* __restrict__ A2f, const bf16* __restrict__ A2b,
    const bf16* __restrict__ Wt, const float* __restrict__ bias, const bf16* H0,
    const int* __restrict__ srcIdx, const int* __restrict__ revIdx,
    bf16* out, int Mrows, int K, int Nsrc) {
  __shared__ __align__(16) bf16 As[128 * 64];
  __shared__ __align__(16) bf16 Bs[256 * 64];
  int tid = threadIdx.x;
  int lane = tid & 63;
  int wave = tid >> 6;
  int wm = wave >> 2, wn = wave & 3;
  int m0 = blockIdx.x * 128;

  // per-thread A staging geometry (2 units of 8 bf16), indices hoisted
  int rowA[2], uA[2];
  int base1[2], base2[2];  // element offsets (fit in int)
#pragma unroll
  for (int r = 0; r < 2; ++r) {
    int unit = r * 512 + tid;
    rowA[r] = unit >> 3;
    uA[r] = unit & 7;
    int rr = m0 + rowA[r];
    if (rr >= Mrows) rr = Mrows - 1;
    if (MODE == 0) {
      base1[r] = clampi(srcIdx[rr], Nsrc) * 256;
      base2[r] = rr * 64;
    } else if (MODE == 1) {
      base1[r] = clampi(srcIdx[rr], Nsrc) * 256;
      base2[r] = clampi(revIdx[rr], Mrows) * 256;
    } else {
      base1[r] = rr * 256;
      base2[r] = rr * 256;
    }
  }

  f32x4 acc[4][4];
#pragma unroll
  for (int i = 0; i < 4; ++i)
#pragma unroll
    for (int j = 0; j < 4; ++j) acc[i][j] = (f32x4){0.f, 0.f, 0.f, 0.f};

  float4 pf[2][2];  // prefetch regs: up to 32B per unit

  auto loadA = [&](int kc) {
    int k0 = kc * 64;
#pragma unroll
    for (int r = 0; r < 2; ++r) {
      int u8 = uA[r] * 8;
      if (MODE == 0) {
        if (k0 < 256) {
          if (XF32) {
            const float* g = A1f + (size_t)(base1[r] + k0 + u8);
            pf[r][0] = *(const float4*)g;
            pf[r][1] = *(const float4*)(g + 4);
          } else {
            pf[r][0] = *(const float4*)(A1b + (size_t)(base1[r] + k0 + u8));
          }
        } else {
          const float* g = A2f + (size_t)(base2[r] + u8);
          pf[r][0] = *(const float4*)g;
          pf[r][1] = *(const float4*)(g + 4);
        }
      } else if (MODE == 1) {
        pf[r][0] = *(const float4*)(A1b + (size_t)(base1[r] + k0 + u8));
        pf[r][1] = *(const float4*)(A2b + (size_t)(base2[r] + k0 + u8));
      } else {
        if (k0 < 256) {
          if (XF32) {
            const float* g = A1f + (size_t)(base1[r] + k0 + u8);
            pf[r][0] = *(const float4*)g;
            pf[r][1] = *(const float4*)(g + 4);
          } else {
            pf[r][0] = *(const float4*)(A1b + (size_t)(base1[r] + k0 + u8));
          }
        } else {
          pf[r][0] = *(const float4*)(A2b + (size_t)(base2[r] + (k0 - 256) + u8));
        }
      }
    }
  };

  auto writeA = [&](int kc) {
    int k0 = kc * 64;
#pragma unroll
    for (int r = 0; r < 2; ++r) {
      int row = rowA[r], us = uA[r] ^ (row & 7);
      bf16x8 v;
      bool cvt32;
      if (MODE == 0) cvt32 = XF32 || (k0 >= 256);
      else if (MODE == 2) cvt32 = XF32 && (k0 < 256);
      else cvt32 = false;
      if (MODE == 1) {
        bf16x8 va = *(bf16x8*)(&pf[r][0]);
        bf16x8 vh = *(bf16x8*)(&pf[r][1]);
#pragma unroll
        for (int j = 0; j < 8; ++j) v[j] = (bf16)((float)va[j] - (float)vh[j]);
      } else if (cvt32) {
        const float* f = (const float*)&pf[r][0];
#pragma unroll
        for (int j = 0; j < 8; ++j) v[j] = (bf16)f[j];
      } else {
        v = *(bf16x8*)(&pf[r][0]);
      }
      *(bf16x8*)(&As[(size_t)(row * 8 + us) * 8]) = v;
    }
  };

  auto loadB = [&](int kc) {
    int k0 = kc * 64;
#pragma unroll
    for (int r = 0; r < 4; ++r) {
      int unit = r * 512 + tid;
      int row = unit >> 3, us = (unit & 7) ^ (row & 7);
      const bf16* g = Wt + (size_t)row * K + k0 + us * 8;
      bf16* l = &Bs[(size_t)(r * 512 + wave * 64) * 8];
      gload16(g, l);
    }
  };

  int nk = K / 64;
  loadA(0);
  for (int kc = 0; kc < nk; ++kc) {
    __syncthreads();   // previous compute done reading LDS; A(kc) regs landed
    writeA(kc);
    loadB(kc);
    __syncthreads();   // ds_writes + B global_load_lds visible
    if (kc + 1 < nk) loadA(kc + 1);  // prefetch next tile's gathers under compute
    // ---- compute: 2 k-subtiles of 32, 32 MFMA per wave ----
#pragma unroll
    for (int s = 0; s < 2; ++s) {
      int kq = s * 4 + (lane >> 4);
      bf16x8 af[4], bfr[4];
#pragma unroll
      for (int i = 0; i < 4; ++i) {
        int arow = wm * 64 + i * 16 + (lane & 15);
        af[i] = *(const bf16x8*)(&As[(size_t)arow * 64 + (size_t)(kq ^ (arow & 7)) * 8]);
      }
#pragma unroll
      for (int j = 0; j < 4; ++j) {
        int brow = wn * 64 + j * 16 + (lane & 15);
        bfr[j] = *(const bf16x8*)(&Bs[(size_t)brow * 64 + (size_t)(kq ^ (brow & 7)) * 8]);
      }
#pragma unroll
      for (int i = 0; i < 4; ++i)
#pragma unroll
        for (int j = 0; j < 4; ++j)
          acc[i][j] = __builtin_amdgcn_mfma_f32_16x16x32_bf16(af[i], bfr[j], acc[i][j], 0, 0, 0);
    }
  }
  // ---- epilogue: D row=(lane>>4)*4+r, col=lane&15 ----
#pragma unroll
  for (int i = 0; i < 4; ++i) {
    int rbase = m0 + wm * 64 + i * 16 + ((lane >> 4) << 2);
#pragma unroll
    for (int j = 0; j < 4; ++j) {
      int col = wn * 64 + j * 16 + (lane & 15);
      float bcol = bias[col];
#pragma unroll
      for (int r = 0; r < 4; ++r) {
        int row = rbase + r;
        if (row < Mrows) {
          float v = acc[i][j][r] + bcol;
          if (MODE == 1) v += (float)H0[(size_t)row * 256 + col];  // read-before-write when out==H0
          v = fmaxf(v, 0.f);
          out[(size_t)row * 256 + col] = (bf16)v;
        }
      }
    }
  }
}

// ---------------- per-level driver ----------------
template <int XF32>
static void run_level(const float* xf, const bf16* xb, const float* ea,
                      const int* src, const int* dst, const int* rev, int E, int N, int depth,
                      const bf16* WiT, const float* bi_, const bf16* WhT, const float* bh_,
                      const bf16* WoT, const float* bo_,
                      bf16* C, bf16* Dd, bf16* Ee, bf16* agg, bf16* h,
                      int* cnt, int* incl, int* offs, int* cursr, int* bsums, int* bexcl,
                      int* elist, hipStream_t stream) {
  // CSR build
  hipMemsetAsync(cnt, 0, (size_t)N * 4, stream);
  hist_kernel<<<(E + 255) / 256, 256, 0, stream>>>(dst, E, cnt, N);
  int nb = (N + 1023) / 1024;
  scan_block_kernel<<<nb, 256, 0, stream>>>(cnt, N, incl, bsums);
  scan_sums_kernel<<<1, 256, 0, stream>>>(bsums, nb, bexcl);
  scan_add_kernel<<<(N + 255) / 256, 256, 0, stream>>>(incl, bexcl, N, offs);
  hipMemsetAsync(cursr, 0, (size_t)N * 4, stream);
  scatter_kernel<<<(E + 255) / 256, 256, 0, stream>>>(dst, E, offs, cursr, elist, N);

  dim3 ge((E + 127) / 128);
  // H0 = relu([x[src], ea] @ Wi + bi) -> C
  gemm_kernel<0, XF32><<<ge, 512, 0, stream>>>(xf, xb, ea, nullptr, WiT, bi_, nullptr, src,
                                               nullptr, C, E, 320, N);
  bf16* Hcur = C;
  for (int it = 0; it < depth - 1; ++it) {
    segsum_kernel<0, 0><<<(N + 3) / 4, 256, 0, stream>>>(Hcur, elist, offs, nullptr, nullptr,
                                                         agg, N);
    bf16* Hn = (it == depth - 2) ? C : ((it & 1) ? Ee : Dd);  // last iter writes H0 in place
    gemm_kernel<1, 0><<<ge, 512, 0, stream>>>(nullptr, agg, nullptr, Hcur, WhT, bh_, C, src,
                                              rev, Hn, E, 256, N);
    Hcur = Hn;
  }
  segsum_kernel<1, XF32><<<(N + 3) / 4, 256, 0, stream>>>(Hcur, elist, offs, xf, xb, agg, N);
  dim3 gn((N + 127) / 128);
  // h = relu([x, M] @ Wo + bo)
  gemm_kernel<2, XF32><<<gn, 512, 0, stream>>>(xf, xb, nullptr, agg, WoT, bo_, nullptr, nullptr,
                                               nullptr, h, N, 512, N);
}

// ---------------- host ----------------
extern "C" void kernel_launch(void* const* d_in, const int* in_sizes, int n_in,
                              void* d_out, int out_size, void* d_ws, size_t ws_size,
                              hipStream_t stream) {
  constexpr int N1 = 102400, E1 = 300000;
  constexpr int N2 = 10240, E2 = 40960;
  constexpr int N3 = 1024, E3 = 4096;
  constexpr int G = 64;
  constexpr int KI = 320, KH = 256, KO = 512;

  const float* x   = (const float*)d_in[0];
  const float* ea1 = (const float*)d_in[1];
  const float* ea2 = (const float*)d_in[2];
  const float* ea3 = (const float*)d_in[3];
  const int* ei1 = (const int*)d_in[4];
  const int* rv1 = (const int*)d_in[5];
  const int* ei2 = (const int*)d_in[6];
  const int* rv2 = (const int*)d_in[7];
  const int* ei3 = (const int*)d_in[8];
  const int* rv3 = (const int*)d_in[9];
  const float *Wi[3], *bi[3], *Wh[3], *bh[3], *Wo[3], *bo[3];
  for (int l = 0; l < 3; ++l) {
    Wi[l] = (const float*)d_in[13 + 6 * l + 0];
    bi[l] = (const float*)d_in[13 + 6 * l + 1];
    Wh[l] = (const float*)d_in[13 + 6 * l + 2];
    bh[l] = (const float*)d_in[13 + 6 * l + 3];
    Wo[l] = (const float*)d_in[13 + 6 * l + 4];
    bo[l] = (const float*)d_in[13 + 6 * l + 5];
  }
  float* outp = (float*)d_out;
  char* ws = (char*)d_ws;

  size_t off = 0;
  auto alloc = [&](size_t b) { size_t o = off; off += (b + 255) & ~(size_t)255; return o; };
  size_t o_wit[3], o_wht[3], o_wot[3];
  for (int l = 0; l < 3; ++l) {
    o_wit[l] = alloc((size_t)256 * KI * 2);
    o_wht[l] = alloc((size_t)256 * KH * 2);
    o_wot[l] = alloc((size_t)256 * KO * 2);
  }
  size_t o_C   = alloc((size_t)E1 * 256 * 2);  // H0 / in-place H_final / h1
  size_t o_D   = alloc((size_t)E1 * 256 * 2);  // ping buffer
  size_t o_E3b = alloc((size_t)E3 * 256 * 2);  // level-3 (depth 4) pong buffer
  size_t o_agg = alloc((size_t)N1 * 256 * 2);
  size_t o_x2  = alloc((size_t)N2 * 256 * 2);
  size_t o_h2  = alloc((size_t)N2 * 256 * 2);
  size_t o_x3  = alloc((size_t)N3 * 256 * 2);
  size_t o_h3  = alloc((size_t)N3 * 256 * 2);
  size_t o_cnt = alloc((size_t)N1 * 4);
  size_t o_inc = alloc((size_t)N1 * 4);
  size_t o_off = alloc((size_t)(N1 + 1) * 4);
  size_t o_cur = alloc((size_t)N1 * 4);
  size_t o_bs  = alloc(1024 * 4);
  size_t o_bx  = alloc(1024 * 4);
  size_t o_el  = alloc((size_t)E1 * 4);

  if (ws_size < off) {  // workspace too small: fail validation cleanly, don't fault
    hipMemsetAsync(d_out, 0, (size_t)out_size * 4, stream);
    return;
  }

  int* cnt   = (int*)(ws + o_cnt);
  int* incl  = (int*)(ws + o_inc);
  int* offs  = (int*)(ws + o_off);
  int* cursr = (int*)(ws + o_cur);
  int* bsums = (int*)(ws + o_bs);
  int* bexcl = (int*)(ws + o_bx);
  int* elist = (int*)(ws + o_el);
  bf16* C    = (bf16*)(ws + o_C);
  bf16* Dd   = (bf16*)(ws + o_D);
  bf16* E3b  = (bf16*)(ws + o_E3b);
  bf16* agg  = (bf16*)(ws + o_agg);
  bf16* x2b  = (bf16*)(ws + o_x2);
  bf16* h2b  = (bf16*)(ws + o_h2);
  bf16* x3b  = (bf16*)(ws + o_x3);
  bf16* h3b  = (bf16*)(ws + o_h3);

  for (int l = 0; l < 3; ++l) {
    wtcvt_kernel<<<(KI * 256 + 255) / 256, 256, 0, stream>>>(Wi[l], (bf16*)(ws + o_wit[l]), KI);
    wtcvt_kernel<<<(KH * 256 + 255) / 256, 256, 0, stream>>>(Wh[l], (bf16*)(ws + o_wht[l]), KH);
    wtcvt_kernel<<<(KO * 256 + 255) / 256, 256, 0, stream>>>(Wo[l], (bf16*)(ws + o_wot[l]), KO);
  }

  // level 1 (x as f32; h1 written into C after final segsum consumed it)
  run_level<1>(x, nullptr, ea1, ei1, ei1 + E1, rv1, E1, N1, 3,
               (bf16*)(ws + o_wit[0]), bi[0], (bf16*)(ws + o_wht[0]), bh[0],
               (bf16*)(ws + o_wot[0]), bo[0], C, Dd, Dd, agg, C,
               cnt, incl, offs, cursr, bsums, bexcl, elist, stream);
  pool_kernel<0><<<(N2 + 3) / 4, 256, 0, stream>>>(C, x2b, nullptr, N2, N1 / N2);

  // level 2 (C/Dd regions are dead now; reuse their space)
  run_level<0>(nullptr, x2b, ea2, ei2, ei2 + E2, rv2, E2, N2, 3,
               (bf16*)(ws + o_wit[1]), bi[1], (bf16*)(ws + o_wht[1]), bh[1],
               (bf16*)(ws + o_wot[1]), bo[1], C, Dd, Dd, agg, h2b,
               cnt, incl, offs, cursr, bsums, bexcl, elist, stream);
  pool_kernel<0><<<(N3 + 3) / 4, 256, 0, stream>>>(h2b, x3b, nullptr, N3, N2 / N3);

  // level 3 (depth 4 -> needs distinct pong buffer E3b)
  run_level<0>(nullptr, x3b, ea3, ei3, ei3 + E3, rv3, E3, N3, 4,
               (bf16*)(ws + o_wit[2]), bi[2], (bf16*)(ws + o_wht[2]), bh[2],
               (bf16*)(ws + o_wot[2]), bo[2], C, Dd, E3b, agg, h3b,
               cnt, incl, offs, cursr, bsums, bexcl, elist, stream);
  pool_kernel<1><<<(G + 3) / 4, 256, 0, stream>>>(h3b, nullptr, outp, G, N3 / G);
}